// Round 1
// 450.966 us; speedup vs baseline: 1.0709x; 1.0709x over previous
//
#include <hip/hip_runtime.h>
#include <math.h>

#define H    24
#define Dh   128
#define LIMG 2048
#define LIP  512
#define DM   3072
#define DIP  1280
#define LK   2560
#define EPSF 1e-6f
#define SM_SCALE 0.08838834764831845f  // 1/sqrt(128)

typedef __attribute__((ext_vector_type(8))) short bf16x8;
typedef __attribute__((ext_vector_type(4))) float f32x4;

typedef const unsigned int __attribute__((address_space(1))) gu32;
typedef unsigned int __attribute__((address_space(3))) lu32;

static __device__ __forceinline__ unsigned short f2bf(float x) {
  union { float f; unsigned u; } v; v.f = x;
  unsigned r = v.u + 0x7fffu + ((v.u >> 16) & 1u);  // RNE
  return (unsigned short)(r >> 16);
}

static __device__ __forceinline__ float bf2f(unsigned short b) {
  union { unsigned u; float f; } v; v.u = ((unsigned)b) << 16;
  return v.f;
}

// ---------------- Kernel 1: e = silu(t_emb) @ w_ada^T + b_ada ----------------
__global__ __launch_bounds__(256) void ada_kernel(
    const float* __restrict__ t_emb, const float* __restrict__ w_ada,
    const float* __restrict__ b_ada, float* __restrict__ e) {
  int j = blockIdx.x;
  int tid = threadIdx.x;
  const float* wrow = w_ada + (long)j * DIP;
  float acc = 0.f;
  for (int k = tid; k < DIP; k += 256) {
    float t = t_emb[k];
    acc += (t / (1.f + expf(-t))) * wrow[k];
  }
#pragma unroll
  for (int m = 1; m < 64; m <<= 1) acc += __shfl_xor(acc, m, 64);
  __shared__ float red[4];
  if ((tid & 63) == 0) red[tid >> 6] = acc;
  __syncthreads();
  if (tid == 0) e[j] = red[0] + red[1] + red[2] + red[3] + b_ada[j];
}

// ---------------- Kernel 2: AdaLayerNorm -> ip_norm as bf16 hi/lo planes ----
__global__ __launch_bounds__(256) void adaln_kernel(
    const float* __restrict__ x, const float* __restrict__ e,
    unsigned short* __restrict__ ipnh, unsigned short* __restrict__ ipnl) {
  int r = blockIdx.x;
  int tid = threadIdx.x;
  const float* xr = x + (long)r * DIP;
  float v[5];
  float s = 0.f, ss = 0.f;
#pragma unroll
  for (int i = 0; i < 5; i++) {
    v[i] = xr[tid + i * 256];
    s += v[i];
    ss += v[i] * v[i];
  }
#pragma unroll
  for (int m = 1; m < 64; m <<= 1) {
    s += __shfl_xor(s, m, 64);
    ss += __shfl_xor(ss, m, 64);
  }
  __shared__ float rs_[4], rss_[4];
  if ((tid & 63) == 0) { rs_[tid >> 6] = s; rss_[tid >> 6] = ss; }
  __syncthreads();
  s = rs_[0] + rs_[1] + rs_[2] + rs_[3];
  ss = rss_[0] + rss_[1] + rss_[2] + rss_[3];
  float mu = s * (1.f / DIP);
  float var = ss * (1.f / DIP) - mu * mu;
  float rstd = rsqrtf(var + EPSF);
  unsigned short* oh = ipnh + (long)r * DIP;
  unsigned short* ol = ipnl + (long)r * DIP;
#pragma unroll
  for (int i = 0; i < 5; i++) {
    int c = tid + i * 256;
    float o = (v[i] - mu) * rstd * (1.f + e[DIP + c]) + e[c];
    unsigned short hb = f2bf(o);
    oh[c] = hb;
    ol[c] = f2bf(o - bf2f(hb));
  }
}

// ---------------- Kernel 3: img K (RMS) -> Kb bf16, img V -> Vt bf16 (transposed) --
// Kb[H][LK][128] row-major; Vt[H][128][LK]. Block = (32 rows, 1 head).
__global__ __launch_bounds__(256) void prep_kernel(
    const float* __restrict__ k_in, const float* __restrict__ v_in,
    const float* __restrict__ g_k,
    unsigned short* __restrict__ Kb, unsigned short* __restrict__ Vt) {
  __shared__ unsigned short Vls[128][33];
  int h = blockIdx.y, l0 = blockIdx.x * 32;
  int tid = threadIdx.x;
  int r = tid >> 3, c = tid & 7;   // 8 threads/row, 16 elems each
  const float* ksrc = k_in + (long)(l0 + r) * DM + h * Dh + c * 16;
  const float* vsrc = v_in + (long)(l0 + r) * DM + h * Dh + c * 16;
  float kv[16], vv[16];
  float ssq = 0.f;
#pragma unroll
  for (int i = 0; i < 4; i++) {
    float4 a = *(const float4*)(ksrc + i * 4);
    float4 b = *(const float4*)(vsrc + i * 4);
    kv[i*4+0]=a.x; kv[i*4+1]=a.y; kv[i*4+2]=a.z; kv[i*4+3]=a.w;
    vv[i*4+0]=b.x; vv[i*4+1]=b.y; vv[i*4+2]=b.z; vv[i*4+3]=b.w;
    ssq += a.x*a.x + a.y*a.y + a.z*a.z + a.w*a.w;
  }
  ssq += __shfl_xor(ssq, 1, 8);
  ssq += __shfl_xor(ssq, 2, 8);
  ssq += __shfl_xor(ssq, 4, 8);
  float rstd = rsqrtf(ssq * (1.f / Dh) + EPSF);
  unsigned short kb[16];
#pragma unroll
  for (int i = 0; i < 16; i++) kb[i] = f2bf(kv[i] * rstd * g_k[c * 16 + i]);
  unsigned short* kdst = Kb + ((long)h * LK + l0 + r) * Dh + c * 16;
  *(uint4*)(kdst) = *(uint4*)(kb);
  *(uint4*)(kdst + 8) = *(uint4*)(kb + 8);
  // transpose V through LDS
#pragma unroll
  for (int i = 0; i < 16; i++) Vls[c * 16 + i][r] = f2bf(vv[i]);
  __syncthreads();
  int d = tid >> 1, half = (tid & 1) * 16;
  unsigned short ov[16];
#pragma unroll
  for (int j = 0; j < 16; j++) ov[j] = Vls[d][half + j];
  unsigned short* vdst = Vt + ((long)h * Dh + d) * LK + l0 + half;
  *(uint4*)(vdst) = *(uint4*)(ov);
  *(uint4*)(vdst + 8) = *(uint4*)(ov + 8);
}

// ---------------- Kernel 4: ip projections via split-bf16 MFMA ----------------
// C[m][n] = sum_k ipn[m][k] * W[n][k]; per block: 64 rows x 128 cols (one head),
// K-step 32. ipn pre-split into hi/lo bf16 planes (adaln); W split in-kernel.
// acc = Ah*Wh + Ah*Wl + Al*Wh  (fp32-quality, lo*lo dropped).
// z=0: RMS(+g_ipk) -> Kb rows 2048+; z=1: transposed -> Vt cols 2048+.
__global__ __launch_bounds__(256) void proj_kernel(
    const unsigned short* __restrict__ Ah, const unsigned short* __restrict__ Al,
    const float* __restrict__ Wk, const float* __restrict__ Wv,
    const float* __restrict__ g_ipk,
    unsigned short* __restrict__ Kb, unsigned short* __restrict__ Vt) {
  // LDS (chunk-major, conflict-free): Ahs/Als [4 kchunk][64 row][8], Whs/Wls [4][128][8]
  __shared__ __align__(16) unsigned short lds[12288];   // 24 KB
  unsigned short* Ahs = lds;
  unsigned short* Als = lds + 2048;
  unsigned short* Whs = lds + 4096;
  unsigned short* Wls = lds + 8192;
  const float* W = blockIdx.z ? Wv : Wk;
  int h = blockIdx.y;
  int m0 = blockIdx.x * 64;
  int tid = threadIdx.x;
  int w = tid >> 6, lane = tid & 63;
  int m = lane & 15, quad = lane >> 4;

  // W source: thread owns row n = tid&127, k-granules c0 and c0+2 (c0 = tid>>7)
  const float* wrow = W + (long)(h * Dh + (tid & 127)) * DIP + ((tid >> 7) << 3);
  // A source: wave w stages k-chunk w, row = lane (linear 16B/lane dest)
  const unsigned short* garow_h = Ah + (long)(m0 + lane) * DIP + w * 8;
  const unsigned short* garow_l = Al + (long)(m0 + lane) * DIP + w * 8;

  f32x4 acc[8];
#pragma unroll
  for (int i = 0; i < 8; i++) acc[i] = (f32x4){0.f, 0.f, 0.f, 0.f};

  float4 wa = *(const float4*)(wrow);
  float4 wb = *(const float4*)(wrow + 4);
  float4 wc = *(const float4*)(wrow + 16);
  float4 wd = *(const float4*)(wrow + 20);

#pragma unroll 1
  for (int k0 = 0; k0 < DIP; k0 += 32) {
    float cur[16] = {wa.x, wa.y, wa.z, wa.w, wb.x, wb.y, wb.z, wb.w,
                     wc.x, wc.y, wc.z, wc.w, wd.x, wd.y, wd.z, wd.w};
    if (k0 + 32 < DIP) {   // prefetch next K-step's W regs (latency hidden under MFMA)
      wa = *(const float4*)(wrow + k0 + 32);
      wb = *(const float4*)(wrow + k0 + 36);
      wc = *(const float4*)(wrow + k0 + 48);
      wd = *(const float4*)(wrow + k0 + 52);
    }
    unsigned short hi[16], lo[16];
#pragma unroll
    for (int i = 0; i < 16; i++) {
      unsigned short hb = f2bf(cur[i]);
      hi[i] = hb;
      lo[i] = f2bf(cur[i] - bf2f(hb));
    }
    __syncthreads();   // all waves done reading previous tile
    __builtin_amdgcn_global_load_lds((gu32*)(garow_h + k0), (lu32*)(Ahs + w * 512), 16, 0, 0);
    __builtin_amdgcn_global_load_lds((gu32*)(garow_l + k0), (lu32*)(Als + w * 512), 16, 0, 0);
    // linear per-wave ds_write dest -> conflict-free
    *(uint4*)(Whs + tid * 8) = *(uint4*)(hi);
    *(uint4*)(Wls + tid * 8) = *(uint4*)(lo);
    *(uint4*)(Whs + (tid + 256) * 8) = *(uint4*)(hi + 8);
    *(uint4*)(Wls + (tid + 256) * 8) = *(uint4*)(lo + 8);
    __syncthreads();   // drains vmcnt+lgkmcnt -> tiles ready

    bf16x8 ahf = *(const bf16x8*)(Ahs + ((quad << 6) + (w << 4) + m) * 8);
    bf16x8 alf = *(const bf16x8*)(Als + ((quad << 6) + (w << 4) + m) * 8);
#pragma unroll
    for (int nt = 0; nt < 8; nt++) {
      bf16x8 bhf = *(const bf16x8*)(Whs + ((quad << 7) + (nt << 4) + m) * 8);
      bf16x8 blf = *(const bf16x8*)(Wls + ((quad << 7) + (nt << 4) + m) * 8);
      acc[nt] = __builtin_amdgcn_mfma_f32_16x16x32_bf16(ahf, bhf, acc[nt], 0, 0, 0);
      acc[nt] = __builtin_amdgcn_mfma_f32_16x16x32_bf16(ahf, blf, acc[nt], 0, 0, 0);
      acc[nt] = __builtin_amdgcn_mfma_f32_16x16x32_bf16(alf, bhf, acc[nt], 0, 0, 0);
    }
  }

  // ---- epilogue: C[row = m0 + w*16 + quad*4 + r][col = nt*16 + m] ----
  if (blockIdx.z == 0) {
    float gkv[8];
#pragma unroll
    for (int nt = 0; nt < 8; nt++) gkv[nt] = g_ipk[nt * 16 + m];
#pragma unroll
    for (int r = 0; r < 4; r++) {
      float ssq = 0.f;
#pragma unroll
      for (int nt = 0; nt < 8; nt++) ssq += acc[nt][r] * acc[nt][r];
      ssq += __shfl_xor(ssq, 1, 16);
      ssq += __shfl_xor(ssq, 2, 16);
      ssq += __shfl_xor(ssq, 4, 16);
      ssq += __shfl_xor(ssq, 8, 16);
      float rstd = rsqrtf(ssq * (1.f / Dh) + EPSF);
      long row = (long)h * LK + LIMG + m0 + w * 16 + quad * 4 + r;
#pragma unroll
      for (int nt = 0; nt < 8; nt++)
        Kb[row * Dh + nt * 16 + m] = f2bf(acc[nt][r] * rstd * gkv[nt]);
    }
  } else {
#pragma unroll
    for (int nt = 0; nt < 8; nt++) {
      ushort4 o;
      o.x = f2bf(acc[nt][0]); o.y = f2bf(acc[nt][1]);
      o.z = f2bf(acc[nt][2]); o.w = f2bf(acc[nt][3]);
      *(ushort4*)(Vt + ((long)h * Dh + nt * 16 + m) * LK + LIMG + m0 + w * 16 + quad * 4) = o;
    }
  }
}

// ---------------- Kernel 5: MFMA flash attention ----------------
// 4 waves; wave owns 16 q-rows (BQ=64). BK=32. Q fp32->RMS->bf16 in registers.
__global__ __launch_bounds__(256, 4) void flash_kernel(
    const float* __restrict__ q_in, const float* __restrict__ g_q,
    const unsigned short* __restrict__ Kb, const unsigned short* __restrict__ Vt,
    float* __restrict__ out) {
  __shared__ __align__(16) unsigned char lds[8192 + 8192 + 5120];
  unsigned short* Ks = (unsigned short*)lds;            // [32 rows][16 granules, XOR-swizzled]
  unsigned short* Vs = (unsigned short*)(lds + 8192);   // [128 d][4 granules]
  unsigned short* Ps = (unsigned short*)(lds + 16384);  // per wave: 16 rows x 40 ushorts
  int tid = threadIdx.x;
  int w = tid >> 6, lid = tid & 63;
  int m = lid & 15, quad = lid >> 4;
  int h = blockIdx.y;
  int q0 = blockIdx.x * 64;
  int qrow = q0 + w * 16 + m;

  // ---- Q: load fp32, RMS over 128 (quad lanes hold disjoint d), g_q, -> A-frags ----
  bf16x8 aq[4];
  {
    float qf[4][8];
    float ssq = 0.f;
    const float* qsrc = q_in + (long)qrow * DM + h * Dh + quad * 8;
#pragma unroll
    for (int ks = 0; ks < 4; ks++) {
      float4 a = *(const float4*)(qsrc + ks * 32);
      float4 b = *(const float4*)(qsrc + ks * 32 + 4);
      qf[ks][0]=a.x; qf[ks][1]=a.y; qf[ks][2]=a.z; qf[ks][3]=a.w;
      qf[ks][4]=b.x; qf[ks][5]=b.y; qf[ks][6]=b.z; qf[ks][7]=b.w;
      ssq += a.x*a.x + a.y*a.y + a.z*a.z + a.w*a.w;
      ssq += b.x*b.x + b.y*b.y + b.z*b.z + b.w*b.w;
    }
    ssq += __shfl_xor(ssq, 16, 64);
    ssq += __shfl_xor(ssq, 32, 64);
    float rstd = rsqrtf(ssq * (1.f / Dh) + EPSF);
    const float* gq = g_q + quad * 8;
#pragma unroll
    for (int ks = 0; ks < 4; ks++) {
      float4 ga = *(const float4*)(gq + ks * 32);
      float4 gb = *(const float4*)(gq + ks * 32 + 4);
      float gg[8] = {ga.x, ga.y, ga.z, ga.w, gb.x, gb.y, gb.z, gb.w};
#pragma unroll
      for (int j = 0; j < 8; j++)
        aq[ks][j] = (short)f2bf(qf[ks][j] * rstd * gg[j]);
    }
  }

  const unsigned short* KbH = Kb + (long)h * LK * Dh;
  const unsigned short* VtH = Vt + (long)h * Dh * LK;
  unsigned short* Pw = Ps + w * (16 * 40);

  f32x4 acc_o[8];
#pragma unroll
  for (int i = 0; i < 8; i++) acc_o[i] = (f32x4){0.f, 0.f, 0.f, 0.f};
  float mrun[4] = {-INFINITY, -INFINITY, -INFINITY, -INFINITY};
  float lrun[4] = {0.f, 0.f, 0.f, 0.f};

#pragma unroll 1
  for (int j0 = 0; j0 < LK; j0 += 32) {
    __syncthreads();   // all waves done reading previous tile
    {
      int sbase = w * 128;
#pragma unroll
      for (int is = 0; is < 2; is++) {   // K tile, swizzled via global address
        int s = sbase + is * 64 + lid;
        int r = s >> 4, cc = s & 15;
        int c = cc ^ (r & 15);
        const unsigned short* g = KbH + (long)(j0 + r) * Dh + c * 8;
        __builtin_amdgcn_global_load_lds((gu32*)g, (lu32*)(Ks + (sbase + is * 64) * 8),
                                         16, 0, 0);
      }
#pragma unroll
      for (int is = 0; is < 2; is++) {   // Vt tile (64B rows interleave banks naturally)
        int s = sbase + is * 64 + lid;
        int d = s >> 2, cc = s & 3;
        const unsigned short* g = VtH + (long)d * LK + j0 + cc * 8;
        __builtin_amdgcn_global_load_lds((gu32*)g, (lu32*)(Vs + (sbase + is * 64) * 8),
                                         16, 0, 0);
      }
    }
    __syncthreads();   // barrier drains vmcnt -> tiles ready

    // ---- S = Q K^T (two 16-wide n-tiles) ----
    f32x4 sc[2];
    sc[0] = (f32x4){0.f, 0.f, 0.f, 0.f};
    sc[1] = (f32x4){0.f, 0.f, 0.f, 0.f};
#pragma unroll
    for (int t = 0; t < 2; t++)
#pragma unroll
      for (int ks = 0; ks < 4; ks++) {
        int rr = t * 16 + m;
        int g = (ks * 4 + quad) ^ m;
        bf16x8 bk = *(const bf16x8*)(Ks + rr * 128 + g * 8);
        sc[t] = __builtin_amdgcn_mfma_f32_16x16x32_bf16(aq[ks], bk, sc[t], 0, 0, 0);
      }

    // ---- online softmax; lane holds rows quad*4+r, cols m and m+16 ----
    float mx[4], al[4], ps0[4], ps1[4];
#pragma unroll
    for (int r = 0; r < 4; r++) {
      float v0 = sc[0][r] * SM_SCALE, v1 = sc[1][r] * SM_SCALE;
      ps0[r] = v0; ps1[r] = v1;
      float mm = fmaxf(v0, v1);
      mm = fmaxf(mm, __shfl_xor(mm, 1, 16));
      mm = fmaxf(mm, __shfl_xor(mm, 2, 16));
      mm = fmaxf(mm, __shfl_xor(mm, 4, 16));
      mm = fmaxf(mm, __shfl_xor(mm, 8, 16));
      mx[r] = mm;
    }
#pragma unroll
    for (int r = 0; r < 4; r++) {
      float mn = fmaxf(mrun[r], mx[r]);
      al[r] = __expf(mrun[r] - mn);
      mrun[r] = mn;
      float p0 = __expf(ps0[r] - mn), p1 = __expf(ps1[r] - mn);
      ps0[r] = p0; ps1[r] = p1;
      float s2 = p0 + p1;
      s2 += __shfl_xor(s2, 1, 16);
      s2 += __shfl_xor(s2, 2, 16);
      s2 += __shfl_xor(s2, 4, 16);
      s2 += __shfl_xor(s2, 8, 16);
      lrun[r] = lrun[r] * al[r] + s2;
    }
    // ---- P: C-layout -> LDS -> A-layout (wave-private region, 80B stride) ----
#pragma unroll
    for (int r = 0; r < 4; r++) {
      Pw[(quad * 4 + r) * 40 + m] = f2bf(ps0[r]);
      Pw[(quad * 4 + r) * 40 + 16 + m] = f2bf(ps1[r]);
    }
    __threadfence_block();
    bf16x8 ap = *(const bf16x8*)(Pw + m * 40 + quad * 8);
#pragma unroll
    for (int dt = 0; dt < 8; dt++) {
      acc_o[dt][0] *= al[0]; acc_o[dt][1] *= al[1];
      acc_o[dt][2] *= al[2]; acc_o[dt][3] *= al[3];
    }
#pragma unroll
    for (int dt = 0; dt < 8; dt++) {
      bf16x8 bv = *(const bf16x8*)(Vs + (dt * 16 + m) * 32 + quad * 8);
      acc_o[dt] = __builtin_amdgcn_mfma_f32_16x16x32_bf16(ap, bv, acc_o[dt], 0, 0, 0);
    }
  }

  // ---- epilogue ----
  float il[4] = {1.f / lrun[0], 1.f / lrun[1], 1.f / lrun[2], 1.f / lrun[3]};
#pragma unroll
  for (int dt = 0; dt < 8; dt++)
#pragma unroll
    for (int r = 0; r < 4; r++)
      out[(long)(q0 + w * 16 + quad * 4 + r) * DM + h * Dh + dt * 16 + m] =
          acc_o[dt][r] * il[r];
}

// ---------------- launch ----------------
extern "C" void kernel_launch(void* const* d_in, const int* in_sizes, int n_in,
                              void* d_out, int out_size, void* d_ws, size_t ws_size,
                              hipStream_t stream) {
  const float* ip_hidden = (const float*)d_in[0];
  const float* img_q     = (const float*)d_in[1];
  const float* img_k     = (const float*)d_in[2];
  const float* img_v     = (const float*)d_in[3];
  const float* t_emb     = (const float*)d_in[4];
  const float* w_ada     = (const float*)d_in[5];
  const float* b_ada     = (const float*)d_in[6];
  const float* w_k_ip    = (const float*)d_in[7];
  const float* w_v_ip    = (const float*)d_in[8];
  const float* g_q       = (const float*)d_in[9];
  const float* g_k       = (const float*)d_in[10];
  const float* g_ipk     = (const float*)d_in[11];

  // workspace layout (bytes):
  //   [0, 16384)                      e  (fp32, 2560 used)
  //   [16384, +1310720)               ipn hi plane (bf16, 512x1280)
  //   [1327104, +1310720)             ipn lo plane
  //   [2637824, +15728640)            Kb  (bf16, 24x2560x128)
  //   [18366464, +15728640)           Vt  (bf16, 24x128x2560)   -> 34.1 MB total
  char* base = (char*)d_ws;
  float* e = (float*)base;
  unsigned short* ipnh = (unsigned short*)(base + 16384);
  unsigned short* ipnl = (unsigned short*)(base + 1327104);
  unsigned short* Kb   = (unsigned short*)(base + 2637824);
  unsigned short* Vt   = Kb + (size_t)H * LK * Dh;
  float* out = (float*)d_out;

  ada_kernel<<<2 * DIP, 256, 0, stream>>>(t_emb, w_ada, b_ada, e);
  adaln_kernel<<<LIP, 256, 0, stream>>>(ip_hidden, e, ipnh, ipnl);
  prep_kernel<<<dim3(LIMG / 32, H), 256, 0, stream>>>(img_k, img_v, g_k, Kb, Vt);
  proj_kernel<<<dim3(LIP / 64, H, 2), 256, 0, stream>>>(ipnh, ipnl, w_k_ip, w_v_ip,
                                                        g_ipk, Kb, Vt);
  flash_kernel<<<dim3(LIMG / 64, H), 256, 0, stream>>>(img_q, g_q, Kb, Vt, out);
}